// Round 1
// baseline (431.610 us; speedup 1.0000x reference)
//
#include <hip/hip_runtime.h>

#define NODES 10000
#define BATCH 8
#define CH    128
#define KNB   16
#define CO    256

__device__ __forceinline__ float4 f4max(float4 a, float4 b) {
  return make_float4(fmaxf(a.x, b.x), fmaxf(a.y, b.y),
                     fmaxf(a.z, b.z), fmaxf(a.w, b.w));
}

// ---------------------------------------------------------------------------
// Transpose W1, Wp (128x128) and W2 (256x256) into c-major Wt[c][d] layout.
// ---------------------------------------------------------------------------
__global__ __launch_bounds__(256) void prep_weights(
    const float* __restrict__ W1, const float* __restrict__ Wp,
    const float* __restrict__ W2,
    float* __restrict__ W1t, float* __restrict__ Wpt, float* __restrict__ W2t)
{
  int i = blockIdx.x * 256 + threadIdx.x;
  if (i < CH * CH) {
    int c = i / CH, d = i % CH;   // Wt[c*CH + d] = W[d*CH + c]
    W1t[i] = W1[d * CH + c];
    Wpt[i] = Wp[d * CH + c];
  }
  if (i < CO * CO) {
    int c = i / CO, d = i % CO;
    W2t[i] = W2[d * CO + c];
  }
}

// ---------------------------------------------------------------------------
// Y[b] = relu(W (128x128) @ X[b] (128xN) + bias)
// Wt is c-major [K][M]. TRANS_OUT=false: Y[b][d][n]; true: Y[b][n][d].
// Block: 256 threads, tile 128 d x 64 n, per-thread 8x4 register tile.
// ---------------------------------------------------------------------------
template<bool TRANS_OUT>
__global__ __launch_bounds__(256) void gemm128(
    const float* __restrict__ Wt, const float* __restrict__ bias,
    const float* __restrict__ X, float* __restrict__ Y)
{
  const int b   = blockIdx.y;
  const int n0  = blockIdx.x * 64;
  const int t   = threadIdx.x;
  const int tdx = t & 15;   // n-quad (16 * 4 = 64 n)
  const int tdy = t >> 4;   // d-oct  (16 * 8 = 128 d)

  __shared__ __align__(16) float Ws[32][128];
  __shared__ __align__(16) float Xs[32][64];

  float acc[8][4];
#pragma unroll
  for (int i = 0; i < 8; ++i)
#pragma unroll
    for (int j = 0; j < 4; ++j) acc[i][j] = 0.f;

  const float* Xb = X + (size_t)b * CH * NODES;

  for (int kc = 0; kc < CH; kc += 32) {
    __syncthreads();
    // stage W chunk: 32x128 = 1024 float4, 4 per thread (contiguous)
#pragma unroll
    for (int j = 0; j < 4; ++j) {
      int f = t + j * 256;
      ((float4*)Ws)[f] = ((const float4*)(Wt + (size_t)kc * CH))[f];
    }
    // stage X chunk: 32x64 = 512 float4, 2 per thread
#pragma unroll
    for (int j = 0; j < 2; ++j) {
      int f  = t + j * 256;
      int c  = f >> 4, nq = f & 15;
      int n  = n0 + nq * 4;
      float4 v = make_float4(0.f, 0.f, 0.f, 0.f);
      if (n < NODES) v = *(const float4*)(Xb + (size_t)(kc + c) * NODES + n);
      *(float4*)&Xs[c][nq * 4] = v;
    }
    __syncthreads();
#pragma unroll 8
    for (int c = 0; c < 32; ++c) {
      const float4 xv = *(const float4*)&Xs[c][tdx * 4];
      const float4 w0 = *(const float4*)&Ws[c][tdy * 8];
      const float4 w1 = *(const float4*)&Ws[c][tdy * 8 + 4];
      const float wv[8] = {w0.x, w0.y, w0.z, w0.w, w1.x, w1.y, w1.z, w1.w};
      const float xa[4] = {xv.x, xv.y, xv.z, xv.w};
#pragma unroll
      for (int i = 0; i < 8; ++i)
#pragma unroll
        for (int j = 0; j < 4; ++j)
          acc[i][j] = fmaf(wv[i], xa[j], acc[i][j]);
    }
  }

  float bs[8];
#pragma unroll
  for (int i = 0; i < 8; ++i) bs[i] = bias[tdy * 8 + i];

  const int n = n0 + tdx * 4;
  if (n < NODES) {
    if (!TRANS_OUT) {
#pragma unroll
      for (int i = 0; i < 8; ++i) {
        float4 v;
        v.x = fmaxf(acc[i][0] + bs[i], 0.f);
        v.y = fmaxf(acc[i][1] + bs[i], 0.f);
        v.z = fmaxf(acc[i][2] + bs[i], 0.f);
        v.w = fmaxf(acc[i][3] + bs[i], 0.f);
        *(float4*)(Y + ((size_t)b * CH + tdy * 8 + i) * NODES + n) = v;
      }
    } else {
#pragma unroll
      for (int j = 0; j < 4; ++j) {
        float4 v0, v1;
        v0.x = fmaxf(acc[0][j] + bs[0], 0.f);
        v0.y = fmaxf(acc[1][j] + bs[1], 0.f);
        v0.z = fmaxf(acc[2][j] + bs[2], 0.f);
        v0.w = fmaxf(acc[3][j] + bs[3], 0.f);
        v1.x = fmaxf(acc[4][j] + bs[4], 0.f);
        v1.y = fmaxf(acc[5][j] + bs[5], 0.f);
        v1.z = fmaxf(acc[6][j] + bs[6], 0.f);
        v1.w = fmaxf(acc[7][j] + bs[7], 0.f);
        float* p = Y + ((size_t)b * NODES + n + j) * CH + tdy * 8;
        *(float4*)p       = v0;
        *(float4*)(p + 4) = v1;
      }
    }
  }
}

// ---------------------------------------------------------------------------
// out[b,:,n] = relu(W2 @ [h[:,n]; max_k z[:, idx[n,k]]] + b2)
// Block: 256 threads, 32 n-columns, 256 d-rows. zt is [B][N][128] so each
// gathered column is one contiguous 512B read (L2-friendly).
// Grid is 1-D with b = bid & 7 so each XCD (round-robin dispatch) mostly
// touches one batch's z slab (5.1 MB ~ L2-resident).
// ---------------------------------------------------------------------------
__global__ __launch_bounds__(256) void out_kernel(
    const float* __restrict__ h, const float* __restrict__ zt,
    const int* __restrict__ e0, const float* __restrict__ W2t,
    const float* __restrict__ b2, float* __restrict__ out)
{
  const int bid = blockIdx.x;
  const int b   = bid & 7;
  const int n0  = (bid >> 3) * 32;
  const int t   = threadIdx.x;

  __shared__ __align__(16) float cats[2 * CH][32];  // 32 KB
  __shared__ int idxs[KNB * 32];                    // [k][nl] layout, 2 KB

  // stage edge indices (transposed to [k][nl] to avoid LDS bank clumping)
#pragma unroll
  for (int j = 0; j < 2; ++j) {
    int f  = t + j * 256;
    int nl = f >> 4, k = f & 15;
    int n  = n0 + nl;
    idxs[k * 32 + nl] = (n < NODES) ? e0[((size_t)b * NODES + n) * KNB + k] : 0;
  }
  // stage h tile into cats rows 0..127
  const float* hb = h + (size_t)b * CH * NODES;
#pragma unroll
  for (int j = 0; j < 4; ++j) {
    int f  = t + j * 256;
    int c  = f >> 3, nq = f & 7;
    int n  = n0 + nq * 4;
    float4 v = make_float4(0.f, 0.f, 0.f, 0.f);
    if (n < NODES) v = *(const float4*)(hb + (size_t)c * NODES + n);
    *(float4*)&cats[c][nq * 4] = v;
  }
  __syncthreads();

  // gather-max into cats rows 128..255. thread = (cg, nl): 16 channels x 1 col
  {
    const int cg = t >> 5, nl = t & 31;
    const float* ztb = zt + (size_t)b * NODES * CH + cg * 16;
    float4 m0 = make_float4(0.f, 0.f, 0.f, 0.f);
    float4 m1 = m0, m2 = m0, m3 = m0;
#pragma unroll
    for (int k = 0; k < KNB; ++k) {
      int jn = idxs[k * 32 + nl];
      const float4* p = (const float4*)(ztb + (size_t)jn * CH);
      m0 = f4max(m0, p[0]);
      m1 = f4max(m1, p[1]);
      m2 = f4max(m2, p[2]);
      m3 = f4max(m3, p[3]);
    }
    // relu outputs are >= 0 so init-0 max is exact
    float* col = &cats[CH + cg * 16][nl];
    col[0 * 32]  = m0.x; col[1 * 32]  = m0.y; col[2 * 32]  = m0.z; col[3 * 32]  = m0.w;
    col[4 * 32]  = m1.x; col[5 * 32]  = m1.y; col[6 * 32]  = m1.z; col[7 * 32]  = m1.w;
    col[8 * 32]  = m2.x; col[9 * 32]  = m2.y; col[10 * 32] = m2.z; col[11 * 32] = m2.w;
    col[12 * 32] = m3.x; col[13 * 32] = m3.y; col[14 * 32] = m3.z; col[15 * 32] = m3.w;
  }
  __syncthreads();

  // GEMM: 256 d x 32 n, K = 256. W2t read direct from global (L1/L2-hot,
  // 8-lane broadcast within each instruction).
  const int tdx = t & 7;    // n-quad (8 * 4 = 32 n)
  const int tdy = t >> 3;   // d-oct  (32 * 8 = 256 d)
  float acc[8][4];
#pragma unroll
  for (int i = 0; i < 8; ++i)
#pragma unroll
    for (int j = 0; j < 4; ++j) acc[i][j] = 0.f;

  const float* Wp2 = W2t + tdy * 8;
#pragma unroll 4
  for (int c = 0; c < 2 * CH; ++c) {
    const float4 xv = *(const float4*)&cats[c][tdx * 4];
    const float4 w0 = *(const float4*)(Wp2 + (size_t)c * CO);
    const float4 w1 = *(const float4*)(Wp2 + (size_t)c * CO + 4);
    const float wv[8] = {w0.x, w0.y, w0.z, w0.w, w1.x, w1.y, w1.z, w1.w};
    const float xa[4] = {xv.x, xv.y, xv.z, xv.w};
#pragma unroll
    for (int i = 0; i < 8; ++i)
#pragma unroll
      for (int j = 0; j < 4; ++j)
        acc[i][j] = fmaf(wv[i], xa[j], acc[i][j]);
  }

  const int n = n0 + tdx * 4;
  if (n < NODES) {
#pragma unroll
    for (int i = 0; i < 8; ++i) {
      const int d  = tdy * 8 + i;
      const float bv = b2[d];
      float4 v;
      v.x = fmaxf(acc[i][0] + bv, 0.f);
      v.y = fmaxf(acc[i][1] + bv, 0.f);
      v.z = fmaxf(acc[i][2] + bv, 0.f);
      v.w = fmaxf(acc[i][3] + bv, 0.f);
      *(float4*)(out + ((size_t)b * CO + d) * NODES + n) = v;
    }
  }
}

// ---------------------------------------------------------------------------
extern "C" void kernel_launch(void* const* d_in, const int* in_sizes, int n_in,
                              void* d_out, int out_size, void* d_ws, size_t ws_size,
                              hipStream_t stream) {
  const float* x  = (const float*)d_in[0];
  const int*   ei = (const int*)d_in[1];   // (2,B,N,K); we use first half
  const float* W1 = (const float*)d_in[2];
  const float* b1 = (const float*)d_in[3];
  const float* Wp = (const float*)d_in[4];
  const float* bp = (const float*)d_in[5];
  const float* W2 = (const float*)d_in[6];
  const float* b2 = (const float*)d_in[7];
  float* out = (float*)d_out;

  float* ws  = (float*)d_ws;
  float* h   = ws;                                   // B*C*N   = 10.24M floats
  float* zt  = h  + (size_t)BATCH * CH * NODES;      // B*N*C   = 10.24M floats
  float* W1t = zt + (size_t)BATCH * NODES * CH;      // 16384
  float* Wpt = W1t + CH * CH;                        // 16384
  float* W2t = Wpt + CH * CH;                        // 65536

  prep_weights<<<256, 256, 0, stream>>>(W1, Wp, W2, W1t, Wpt, W2t);

  dim3 g1((NODES + 63) / 64, BATCH);
  gemm128<false><<<g1, 256, 0, stream>>>(W1t, b1, x, h);    // h  = relu(W1 x + b1)
  gemm128<true ><<<g1, 256, 0, stream>>>(Wpt, bp, h, zt);   // zt = relu(Wp h + bp)^T

  out_kernel<<<dim3(8 * ((NODES + 31) / 32)), 256, 0, stream>>>(
      h, zt, ei, W2t, b2, out);
}

// Round 2
// 229.669 us; speedup vs baseline: 1.8793x; 1.8793x over previous
//
#include <hip/hip_runtime.h>

#define NODES 10000
#define BATCH 8
#define CH    128
#define KNB   16
#define CO    256

typedef __bf16 bf16x8 __attribute__((ext_vector_type(8)));
typedef float  f32x4  __attribute__((ext_vector_type(4)));

__device__ __forceinline__ unsigned short f2bf(float f) {
  unsigned u = __float_as_uint(f);
  u = (u + 0x7FFFu + ((u >> 16) & 1u)) >> 16;   // RNE
  return (unsigned short)u;
}

// max of two packed non-negative bf16 == packed u16 max (relu guarantees >=0)
__device__ __forceinline__ unsigned pkmax(unsigned a, unsigned b) {
  unsigned d;
  asm("v_pk_max_u16 %0, %1, %2" : "=v"(d) : "v"(a), "v"(b));
  return d;
}

__device__ __forceinline__ bf16x8 asbf8(uint4 u) {
  union { uint4 u; bf16x8 b; } c; c.u = u; return c.b;
}

// ---------------------------------------------------------------------------
// fp32 -> bf16 weight conversion (layouts stay row-major [d][k])
// ---------------------------------------------------------------------------
__global__ __launch_bounds__(256) void prep(
    const float* __restrict__ W1, const float* __restrict__ Wp,
    const float* __restrict__ W2,
    unsigned short* __restrict__ W1b, unsigned short* __restrict__ Wpb,
    unsigned short* __restrict__ W2b)
{
  int i = blockIdx.x * 256 + threadIdx.x;   // float4 index, 24576 total
  const float* src; unsigned short* dst; int off;
  if (i < 4096)      { src = W1; dst = W1b; off = i; }
  else if (i < 8192) { src = Wp; dst = Wpb; off = i - 4096; }
  else               { src = W2; dst = W2b; off = i - 8192; }
  float4 v = ((const float4*)src)[off];
  ushort4 o;
  o.x = f2bf(v.x); o.y = f2bf(v.y); o.z = f2bf(v.z); o.w = f2bf(v.w);
  ((ushort4*)dst)[off] = o;
}

// ---------------------------------------------------------------------------
// Out[b][n][d] = bf16(relu(W @ In + bias)), W 128x128.
// MODE 0: In = fp32 x [b][c][n] (transpose-convert on stage)
// MODE 1: In = bf16 [b][n][c] node-major (direct stage)
// Block: 256 thr / 4 waves, tile 64 nodes x 128 d, K=128 in one shot.
// LDS B-tile node-major, 16B chunks XOR-swizzled by (n&7) -> conflict-light.
// A fragments loaded straight from global (32 KB, L2-hot).
// ---------------------------------------------------------------------------
template<int MODE>
__global__ __launch_bounds__(256) void gemm_node(
    const unsigned short* __restrict__ Wb, const float* __restrict__ bias,
    const void* __restrict__ In, unsigned short* __restrict__ Out)
{
  const int b  = blockIdx.y;
  const int n0 = blockIdx.x * 64;
  const int t  = threadIdx.x;
  const int lane = t & 63, w = t >> 6;
  const int lm = lane & 15, q = lane >> 4;

  __shared__ unsigned short Bt[64 * 128];   // 16 KB, swizzled
  char* BtB = (char*)Bt;

  if (MODE == 0) {
    const float* X = (const float*)In + (size_t)b * CH * NODES;
#pragma unroll
    for (int rep = 0; rep < 4; ++rep) {
      int flat = t + rep * 256;
      int c2 = flat >> 4, n4 = flat & 15;
      int c  = c2 * 2;
      int gn = n0 + n4 * 4;
      float4 a0 = make_float4(0.f,0.f,0.f,0.f), a1 = a0;
      if (gn < NODES) {
        a0 = *(const float4*)(X + (size_t)c * NODES + gn);
        a1 = *(const float4*)(X + (size_t)(c + 1) * NODES + gn);
      }
      float v0[4] = {a0.x, a0.y, a0.z, a0.w};
      float v1[4] = {a1.x, a1.y, a1.z, a1.w};
#pragma unroll
      for (int i = 0; i < 4; ++i) {
        int nn = n4 * 4 + i;
        unsigned pk = (unsigned)f2bf(v0[i]) | ((unsigned)f2bf(v1[i]) << 16);
        int phys = nn * 256 + (((c2 >> 2) ^ (nn & 7)) << 4) + ((c2 & 3) << 2);
        *(unsigned*)(BtB + phys) = pk;
      }
    }
  } else {
    const unsigned short* H = (const unsigned short*)In + (size_t)b * NODES * CH;
#pragma unroll
    for (int rep = 0; rep < 4; ++rep) {
      int flat = t + rep * 256;
      int nl = flat >> 4, k16 = flat & 15;
      int gn = n0 + nl;
      uint4 v = make_uint4(0u,0u,0u,0u);
      if (gn < NODES) v = *(const uint4*)(H + (size_t)gn * CH + k16 * 8);
      int phys = nl * 256 + ((k16 ^ (nl & 7)) << 4);
      *(uint4*)(BtB + phys) = v;
    }
  }

  // wave mapping: d-half = w&1, n-pair (2x16) = w>>1
  const int d0  = (w & 1) * 64;
  const int nbw = (w >> 1) * 32;

  uint4 af[4][4];   // [dt][kt] A fragments, d = d0+dt*16+lm, k = kt*32+q*8
#pragma unroll
  for (int dt = 0; dt < 4; ++dt)
#pragma unroll
    for (int kt = 0; kt < 4; ++kt)
      af[dt][kt] = *(const uint4*)(Wb + (d0 + dt * 16 + lm) * CH + kt * 32 + q * 8);

  __syncthreads();

  f32x4 acc[4][2];
#pragma unroll
  for (int dt = 0; dt < 4; ++dt)
#pragma unroll
    for (int nt = 0; nt < 2; ++nt) acc[dt][nt] = (f32x4){0.f,0.f,0.f,0.f};

#pragma unroll
  for (int kt = 0; kt < 4; ++kt) {
#pragma unroll
    for (int nt = 0; nt < 2; ++nt) {
      int nl = nbw + nt * 16 + lm;
      int chunk = kt * 4 + q;
      int phys = nl * 256 + ((chunk ^ (nl & 7)) << 4);
      bf16x8 bb = asbf8(*(const uint4*)(BtB + phys));
#pragma unroll
      for (int dt = 0; dt < 4; ++dt)
        acc[dt][nt] = __builtin_amdgcn_mfma_f32_16x16x32_bf16(
            asbf8(af[dt][kt]), bb, acc[dt][nt], 0, 0, 0);
    }
  }

  // epilogue: D[row=q*4+r][col=lm] ; row -> d, col -> node
#pragma unroll
  for (int dt = 0; dt < 4; ++dt) {
    int dbase = d0 + dt * 16 + q * 4;
    float4 bi = *(const float4*)(bias + dbase);
    float bv[4] = {bi.x, bi.y, bi.z, bi.w};
#pragma unroll
    for (int nt = 0; nt < 2; ++nt) {
      int gn = n0 + nbw + nt * 16 + lm;
      if (gn < NODES) {
        ushort4 o;
        o.x = f2bf(fmaxf(acc[dt][nt][0] + bv[0], 0.f));
        o.y = f2bf(fmaxf(acc[dt][nt][1] + bv[1], 0.f));
        o.z = f2bf(fmaxf(acc[dt][nt][2] + bv[2], 0.f));
        o.w = f2bf(fmaxf(acc[dt][nt][3] + bv[3], 0.f));
        *(ushort4*)(Out + ((size_t)b * NODES + gn) * CH + dbase) = o;
      }
    }
  }
}

// ---------------------------------------------------------------------------
// out[b][d][n] = relu(W2 @ [h[n]; max_k z[idx[n,k]]] + b2), d=256, K=256.
// Block: 256 thr / 4 waves, 64-node tile. Gather-max in packed-u16 bf16.
// cat LDS: 64 rows x 512B, XOR-swizzled chunks. A (W2) from global, dbuf.
// b = bid&7 -> per-XCD batch affinity; z slab 2.56 MB fits 4 MB XCD L2.
// ---------------------------------------------------------------------------
__global__ __launch_bounds__(256) void out_kernel(
    const unsigned short* __restrict__ h_t, const unsigned short* __restrict__ z_t,
    const int* __restrict__ e0, const unsigned short* __restrict__ W2b,
    const float* __restrict__ b2, float* __restrict__ out)
{
  const int bid = blockIdx.x;
  const int b   = bid & 7;
  const int n0  = (bid >> 3) * 64;
  const int t   = threadIdx.x;
  const int lane = t & 63, w = t >> 6;
  const int lm = lane & 15, q = lane >> 4;

  __shared__ unsigned short cat[64 * 256];   // 32 KB, swizzled
  char* catB = (char*)cat;

  // stage h -> cat channels 0..127
  {
    const unsigned short* H = h_t + (size_t)b * NODES * CH;
#pragma unroll
    for (int rep = 0; rep < 4; ++rep) {
      int flat = t + rep * 256;
      int nl = flat >> 4, k16 = flat & 15;
      int gn = n0 + nl;
      uint4 v = make_uint4(0u,0u,0u,0u);
      if (gn < NODES) v = *(const uint4*)(H + (size_t)gn * CH + k16 * 8);
      int phys = nl * 512 + ((k16 ^ (nl & 7)) << 4);
      *(uint4*)(catB + phys) = v;
    }
  }

  // gather-max -> cat channels 128..255 ; thread = (node nl, 32-ch group cg)
  {
    const int nl = t & 63, cg = t >> 6;
    int gn = n0 + nl; if (gn > NODES - 1) gn = NODES - 1;
    const int* ep = e0 + ((size_t)b * NODES + gn) * KNB;
    const char* Z = (const char*)z_t + (size_t)b * NODES * CH * 2 + cg * 64;
    uint4 m0 = make_uint4(0u,0u,0u,0u), m1 = m0, m2 = m0, m3 = m0;
#pragma unroll
    for (int jq = 0; jq < 4; ++jq) {
      uint4 iv = *(const uint4*)(ep + jq * 4);
      unsigned idx4[4] = {iv.x, iv.y, iv.z, iv.w};
#pragma unroll
      for (int jj = 0; jj < 4; ++jj) {
        const uint4* p = (const uint4*)(Z + (size_t)idx4[jj] * (CH * 2));
        uint4 v0 = p[0], v1 = p[1], v2 = p[2], v3 = p[3];
        m0.x = pkmax(m0.x, v0.x); m0.y = pkmax(m0.y, v0.y);
        m0.z = pkmax(m0.z, v0.z); m0.w = pkmax(m0.w, v0.w);
        m1.x = pkmax(m1.x, v1.x); m1.y = pkmax(m1.y, v1.y);
        m1.z = pkmax(m1.z, v1.z); m1.w = pkmax(m1.w, v1.w);
        m2.x = pkmax(m2.x, v2.x); m2.y = pkmax(m2.y, v2.y);
        m2.z = pkmax(m2.z, v2.z); m2.w = pkmax(m2.w, v2.w);
        m3.x = pkmax(m3.x, v3.x); m3.y = pkmax(m3.y, v3.y);
        m3.z = pkmax(m3.z, v3.z); m3.w = pkmax(m3.w, v3.w);
      }
    }
    uint4 mm[4] = {m0, m1, m2, m3};
#pragma unroll
    for (int j = 0; j < 4; ++j) {
      int chunk = 16 + cg * 4 + j;
      int phys = nl * 512 + ((chunk ^ (nl & 7)) << 4);
      *(uint4*)(catB + phys) = mm[j];
    }
  }

  __syncthreads();

  // MFMA: wave w -> d in [64w, 64w+64), all 64 nodes, K=256
  const int d0 = w * 64;
  f32x4 acc[4][4];
#pragma unroll
  for (int dt = 0; dt < 4; ++dt)
#pragma unroll
    for (int nt = 0; nt < 4; ++nt) acc[dt][nt] = (f32x4){0.f,0.f,0.f,0.f};

  uint4 acur[4], anxt[4];
#pragma unroll
  for (int dt = 0; dt < 4; ++dt)
    acur[dt] = *(const uint4*)(W2b + (d0 + dt * 16 + lm) * CO + q * 8);

#pragma unroll
  for (int kt = 0; kt < 8; ++kt) {
    if (kt < 7) {
#pragma unroll
      for (int dt = 0; dt < 4; ++dt)
        anxt[dt] = *(const uint4*)(W2b + (d0 + dt * 16 + lm) * CO
                                   + (kt + 1) * 32 + q * 8);
    }
#pragma unroll
    for (int nt = 0; nt < 4; ++nt) {
      int nl = nt * 16 + lm;
      int chunk = kt * 4 + q;
      int phys = nl * 512 + ((chunk ^ (nl & 7)) << 4);
      bf16x8 bb = asbf8(*(const uint4*)(catB + phys));
#pragma unroll
      for (int dt = 0; dt < 4; ++dt)
        acc[dt][nt] = __builtin_amdgcn_mfma_f32_16x16x32_bf16(
            asbf8(acur[dt]), bb, acc[dt][nt], 0, 0, 0);
    }
#pragma unroll
    for (int dt = 0; dt < 4; ++dt) acur[dt] = anxt[dt];
  }

  // epilogue: fp32 out [b][d][n]; each vreg store = 4 x 64B segments
#pragma unroll
  for (int dt = 0; dt < 4; ++dt) {
    int dbase = d0 + dt * 16 + q * 4;
    float4 bi = *(const float4*)(b2 + dbase);
    float bv[4] = {bi.x, bi.y, bi.z, bi.w};
#pragma unroll
    for (int nt = 0; nt < 4; ++nt) {
      int gn = n0 + nt * 16 + lm;
      if (gn < NODES) {
        float* op = out + ((size_t)(b * CO + dbase) * NODES) + gn;
#pragma unroll
        for (int r = 0; r < 4; ++r)
          op[(size_t)r * NODES] = fmaxf(acc[dt][nt][r] + bv[r], 0.f);
      }
    }
  }
}

// ---------------------------------------------------------------------------
extern "C" void kernel_launch(void* const* d_in, const int* in_sizes, int n_in,
                              void* d_out, int out_size, void* d_ws, size_t ws_size,
                              hipStream_t stream) {
  const float* x  = (const float*)d_in[0];
  const int*   ei = (const int*)d_in[1];   // (2,B,N,K); first half = targets
  const float* W1 = (const float*)d_in[2];
  const float* b1 = (const float*)d_in[3];
  const float* Wp = (const float*)d_in[4];
  const float* bp = (const float*)d_in[5];
  const float* W2 = (const float*)d_in[6];
  const float* b2 = (const float*)d_in[7];
  float* out = (float*)d_out;

  unsigned short* ws  = (unsigned short*)d_ws;
  unsigned short* h_t = ws;                                   // [B][N][128] bf16
  unsigned short* z_t = h_t + (size_t)BATCH * NODES * CH;     // [B][N][128] bf16
  unsigned short* W1b = z_t + (size_t)BATCH * NODES * CH;
  unsigned short* Wpb = W1b + CH * CH;
  unsigned short* W2b = Wpb + CH * CH;

  prep<<<96, 256, 0, stream>>>(W1, Wp, W2, W1b, Wpb, W2b);

  dim3 g((NODES + 63) / 64, BATCH);
  gemm_node<0><<<g, 256, 0, stream>>>(W1b, b1, x, h_t);   // h = relu(W1 x + b1)
  gemm_node<1><<<g, 256, 0, stream>>>(Wpb, bp, h_t, z_t); // z = relu(Wp h + bp)

  out_kernel<<<8 * ((NODES + 63) / 64), 256, 0, stream>>>(
      h_t, z_t, ei, W2b, b2, out);
}

// Round 3
// 203.898 us; speedup vs baseline: 2.1168x; 1.1264x over previous
//
#include <hip/hip_runtime.h>

#define NODES 10000
#define BATCH 8
#define CH    128
#define KNB   16
#define CO    256

typedef __bf16 bf16x8 __attribute__((ext_vector_type(8)));
typedef float  f32x4  __attribute__((ext_vector_type(4)));

__device__ __forceinline__ unsigned short f2bf(float f) {
  unsigned u = __float_as_uint(f);
  u = (u + 0x7FFFu + ((u >> 16) & 1u)) >> 16;   // RNE
  return (unsigned short)u;
}

// max of packed non-negative bf16 == packed u16 max (relu guarantees >=0)
__device__ __forceinline__ unsigned pkmax(unsigned a, unsigned b) {
  unsigned d;
  asm("v_pk_max_u16 %0, %1, %2" : "=v"(d) : "v"(a), "v"(b));
  return d;
}
__device__ __forceinline__ uint4 pkmax4(uint4 a, uint4 b) {
  a.x = pkmax(a.x, b.x); a.y = pkmax(a.y, b.y);
  a.z = pkmax(a.z, b.z); a.w = pkmax(a.w, b.w);
  return a;
}
__device__ __forceinline__ bf16x8 asbf8(uint4 u) {
  union { uint4 u; bf16x8 b; } c; c.u = u; return c.b;
}

// ---------------------------------------------------------------------------
// fp32 -> bf16 weight conversion (row-major [d][k] kept)
// ---------------------------------------------------------------------------
__global__ __launch_bounds__(256) void prep(
    const float* __restrict__ W1, const float* __restrict__ Wp,
    const float* __restrict__ W2,
    unsigned short* __restrict__ W1b, unsigned short* __restrict__ Wpb,
    unsigned short* __restrict__ W2b)
{
  int i = blockIdx.x * 256 + threadIdx.x;   // float4 index, 24576 total
  const float* src; unsigned short* dst; int off;
  if (i < 4096)      { src = W1; dst = W1b; off = i; }
  else if (i < 8192) { src = Wp; dst = Wpb; off = i - 4096; }
  else               { src = W2; dst = W2b; off = i - 8192; }
  float4 v = ((const float4*)src)[off];
  ushort4 o;
  o.x = f2bf(v.x); o.y = f2bf(v.y); o.z = f2bf(v.z); o.w = f2bf(v.w);
  ((ushort4*)dst)[off] = o;
}

// ---------------------------------------------------------------------------
// Fused: h = relu(W1 x + b1); z = relu(Wp h + bp). Both written node-major
// bf16 [b][n][128]. Block: 256 thr / 4 waves, 64-node tile, K=128 one shot.
// Phase 1 MFMA reads x-tile from LDS Bt; epilogue writes h to global AND to
// LDS Ht (B-fragment layout); phase 2 MFMA reads Ht. One x read, no h
// round-trip through HBM for the second GEMM.
// ---------------------------------------------------------------------------
__global__ __launch_bounds__(256) void fused_hz(
    const unsigned short* __restrict__ W1b, const float* __restrict__ b1,
    const unsigned short* __restrict__ Wpb, const float* __restrict__ bp,
    const float* __restrict__ x,
    unsigned short* __restrict__ h_t, unsigned short* __restrict__ z_t)
{
  const int b  = blockIdx.y;
  const int n0 = blockIdx.x * 64;
  const int t  = threadIdx.x;
  const int lane = t & 63, w = t >> 6;
  const int lm = lane & 15, q = lane >> 4;

  __shared__ __align__(16) unsigned short Bt[64 * 128];   // x tile, 16 KB
  __shared__ __align__(16) unsigned short Ht[64 * 128];   // h tile, 16 KB
  char* BtB = (char*)Bt;
  char* HtB = (char*)Ht;

  // ---- stage x: fp32 [b][c][n] -> bf16 [n][c], XOR-swizzled 16B chunks
  {
    const float* X = x + (size_t)b * CH * NODES;
#pragma unroll
    for (int rep = 0; rep < 4; ++rep) {
      int flat = t + rep * 256;
      int c2 = flat >> 4, n4 = flat & 15;
      int c  = c2 * 2;
      int gn = n0 + n4 * 4;
      float4 a0 = make_float4(0.f,0.f,0.f,0.f), a1 = a0;
      if (gn < NODES) {
        a0 = *(const float4*)(X + (size_t)c * NODES + gn);
        a1 = *(const float4*)(X + (size_t)(c + 1) * NODES + gn);
      }
      float v0[4] = {a0.x, a0.y, a0.z, a0.w};
      float v1[4] = {a1.x, a1.y, a1.z, a1.w};
#pragma unroll
      for (int i = 0; i < 4; ++i) {
        int nn = n4 * 4 + i;
        unsigned pk = (unsigned)f2bf(v0[i]) | ((unsigned)f2bf(v1[i]) << 16);
        int phys = nn * 256 + (((c2 >> 2) ^ (nn & 7)) << 4) + ((c2 & 3) << 2);
        *(unsigned*)(BtB + phys) = pk;
      }
    }
  }

  const int d0  = (w & 1) * 64;      // d-half for this wave
  const int nbw = (w >> 1) * 32;     // node-pair base

  // W1 A-fragments (global, L2-hot)
  uint4 af[4][4];
#pragma unroll
  for (int dt = 0; dt < 4; ++dt)
#pragma unroll
    for (int kt = 0; kt < 4; ++kt)
      af[dt][kt] = *(const uint4*)(W1b + (d0 + dt*16 + lm) * CH + kt*32 + q*8);

  __syncthreads();

  // ---- phase 1 MFMA: h-tile
  f32x4 acc[4][2];
#pragma unroll
  for (int dt = 0; dt < 4; ++dt)
#pragma unroll
    for (int nt = 0; nt < 2; ++nt) acc[dt][nt] = (f32x4){0.f,0.f,0.f,0.f};

#pragma unroll
  for (int kt = 0; kt < 4; ++kt)
#pragma unroll
    for (int nt = 0; nt < 2; ++nt) {
      int nl = nbw + nt * 16 + lm;
      int chunk = kt * 4 + q;
      int phys = nl * 256 + ((chunk ^ (nl & 7)) << 4);
      bf16x8 bb = asbf8(*(const uint4*)(BtB + phys));
#pragma unroll
      for (int dt = 0; dt < 4; ++dt)
        acc[dt][nt] = __builtin_amdgcn_mfma_f32_16x16x32_bf16(
            asbf8(af[dt][kt]), bb, acc[dt][nt], 0, 0, 0);
    }

  // Wp A-fragments for phase 2 (issue loads before the barrier)
  uint4 af2[4][4];
#pragma unroll
  for (int dt = 0; dt < 4; ++dt)
#pragma unroll
    for (int kt = 0; kt < 4; ++kt)
      af2[dt][kt] = *(const uint4*)(Wpb + (d0 + dt*16 + lm) * CH + kt*32 + q*8);

  // ---- epilogue 1: bias+relu+bf16 -> h_t global + Ht LDS (B-frag layout)
#pragma unroll
  for (int dt = 0; dt < 4; ++dt) {
    int dbase = d0 + dt * 16 + q * 4;
    float4 bi = *(const float4*)(b1 + dbase);
    float bv[4] = {bi.x, bi.y, bi.z, bi.w};
#pragma unroll
    for (int nt = 0; nt < 2; ++nt) {
      int nl = nbw + nt * 16 + lm;
      int gn = n0 + nl;
      ushort4 o;
      o.x = f2bf(fmaxf(acc[dt][nt][0] + bv[0], 0.f));
      o.y = f2bf(fmaxf(acc[dt][nt][1] + bv[1], 0.f));
      o.z = f2bf(fmaxf(acc[dt][nt][2] + bv[2], 0.f));
      o.w = f2bf(fmaxf(acc[dt][nt][3] + bv[3], 0.f));
      int chunk = dbase >> 3;
      int phys  = nl * 256 + ((chunk ^ (nl & 7)) << 4) + ((q & 1) << 3);
      *(ushort4*)(HtB + phys) = o;
      if (gn < NODES)
        *(ushort4*)(h_t + ((size_t)b * NODES + gn) * CH + dbase) = o;
    }
  }

  __syncthreads();

  // ---- phase 2 MFMA: z-tile from Ht
#pragma unroll
  for (int dt = 0; dt < 4; ++dt)
#pragma unroll
    for (int nt = 0; nt < 2; ++nt) acc[dt][nt] = (f32x4){0.f,0.f,0.f,0.f};

#pragma unroll
  for (int kt = 0; kt < 4; ++kt)
#pragma unroll
    for (int nt = 0; nt < 2; ++nt) {
      int nl = nbw + nt * 16 + lm;
      int chunk = kt * 4 + q;
      int phys = nl * 256 + ((chunk ^ (nl & 7)) << 4);
      bf16x8 bb = asbf8(*(const uint4*)(HtB + phys));
#pragma unroll
      for (int dt = 0; dt < 4; ++dt)
        acc[dt][nt] = __builtin_amdgcn_mfma_f32_16x16x32_bf16(
            asbf8(af2[dt][kt]), bb, acc[dt][nt], 0, 0, 0);
    }

  // ---- epilogue 2 -> z_t global
#pragma unroll
  for (int dt = 0; dt < 4; ++dt) {
    int dbase = d0 + dt * 16 + q * 4;
    float4 bi = *(const float4*)(bp + dbase);
    float bv[4] = {bi.x, bi.y, bi.z, bi.w};
#pragma unroll
    for (int nt = 0; nt < 2; ++nt) {
      int gn = n0 + nbw + nt * 16 + lm;
      if (gn < NODES) {
        ushort4 o;
        o.x = f2bf(fmaxf(acc[dt][nt][0] + bv[0], 0.f));
        o.y = f2bf(fmaxf(acc[dt][nt][1] + bv[1], 0.f));
        o.z = f2bf(fmaxf(acc[dt][nt][2] + bv[2], 0.f));
        o.w = f2bf(fmaxf(acc[dt][nt][3] + bv[3], 0.f));
        *(ushort4*)(z_t + ((size_t)b * NODES + gn) * CH + dbase) = o;
      }
    }
  }
}

// ---------------------------------------------------------------------------
// out[b][d][n] = relu(W2 @ [h[n]; max_k z[idx[n,k]]] + b2), d=256, K=256.
// Gather remapped to (node = t>>2, chunk = t&3): each lane-quad reads a
// contiguous 64B of one neighbor column -> coalesced 64B L2 transactions
// (4x fewer than per-lane 16B scatter). b = bid&7 keeps each batch's 2.56MB
// z slab affine to one XCD L2.
// ---------------------------------------------------------------------------
__global__ __launch_bounds__(256) void out_kernel(
    const unsigned short* __restrict__ h_t, const unsigned short* __restrict__ z_t,
    const int* __restrict__ e0, const unsigned short* __restrict__ W2b,
    const float* __restrict__ b2, float* __restrict__ out)
{
  const int bid = blockIdx.x;
  const int b   = bid & 7;
  const int n0  = (bid >> 3) * 64;
  const int t   = threadIdx.x;
  const int lane = t & 63, w = t >> 6;
  const int lm = lane & 15, q = lane >> 4;

  __shared__ __align__(16) unsigned short cat[64 * 256];  // 32 KB, swizzled
  __shared__ __align__(16) int idxs[64 * KNB];            // [nl][k], 4 KB
  char* catB = (char*)cat;

  // ---- stage edge indices: thread (nl = t>>2, jq = t&3) reads 4 ints
  {
    int nl = t >> 2, jq = t & 3;
    int gn = n0 + nl; if (gn > NODES - 1) gn = NODES - 1;
    uint4 iv = *(const uint4*)(e0 + ((size_t)b * NODES + gn) * KNB + jq * 4);
    *(uint4*)&idxs[nl * KNB + jq * 4] = iv;
  }
  __syncthreads();

  // ---- gather-max (coalesced): thread = (nl = t>>2, c = t&3)
  {
    const int nl = t >> 2, c = t & 3;
    const char* Z = (const char*)z_t + (size_t)b * NODES * CH * 2 + c * 16;
    uint4 m[4];
#pragma unroll
    for (int cg = 0; cg < 4; ++cg) m[cg] = make_uint4(0u, 0u, 0u, 0u);
#pragma unroll
    for (int k = 0; k < KNB; ++k) {
      int jn = idxs[nl * KNB + k];
      const char* p = Z + (size_t)jn * (CH * 2);
#pragma unroll
      for (int cg = 0; cg < 4; ++cg)
        m[cg] = pkmax4(m[cg], *(const uint4*)(p + cg * 64));
    }
#pragma unroll
    for (int cg = 0; cg < 4; ++cg) {
      int chunk = 16 + cg * 4 + c;
      int phys = nl * 512 + ((chunk ^ (nl & 7)) << 4);
      *(uint4*)(catB + phys) = m[cg];
    }
  }

  // ---- stage h -> cat chunks 0..15
  {
    const unsigned short* H = h_t + (size_t)b * NODES * CH;
#pragma unroll
    for (int rep = 0; rep < 4; ++rep) {
      int flat = t + rep * 256;
      int nl = flat >> 4, k16 = flat & 15;
      int gn = n0 + nl;
      uint4 v = make_uint4(0u, 0u, 0u, 0u);
      if (gn < NODES) v = *(const uint4*)(H + (size_t)gn * CH + k16 * 8);
      int phys = nl * 512 + ((k16 ^ (nl & 7)) << 4);
      *(uint4*)(catB + phys) = v;
    }
  }

  __syncthreads();

  // ---- MFMA: wave w -> d in [64w, 64w+64), 64 nodes, K=256, W2 dbuf
  const int d0 = w * 64;
  f32x4 acc[4][4];
#pragma unroll
  for (int dt = 0; dt < 4; ++dt)
#pragma unroll
    for (int nt = 0; nt < 4; ++nt) acc[dt][nt] = (f32x4){0.f, 0.f, 0.f, 0.f};

  uint4 acur[4], anxt[4];
#pragma unroll
  for (int dt = 0; dt < 4; ++dt)
    acur[dt] = *(const uint4*)(W2b + (d0 + dt * 16 + lm) * CO + q * 8);

#pragma unroll
  for (int kt = 0; kt < 8; ++kt) {
    if (kt < 7) {
#pragma unroll
      for (int dt = 0; dt < 4; ++dt)
        anxt[dt] = *(const uint4*)(W2b + (d0 + dt * 16 + lm) * CO
                                   + (kt + 1) * 32 + q * 8);
    }
#pragma unroll
    for (int nt = 0; nt < 4; ++nt) {
      int nl = nt * 16 + lm;
      int chunk = kt * 4 + q;
      int phys = nl * 512 + ((chunk ^ (nl & 7)) << 4);
      bf16x8 bb = asbf8(*(const uint4*)(catB + phys));
#pragma unroll
      for (int dt = 0; dt < 4; ++dt)
        acc[dt][nt] = __builtin_amdgcn_mfma_f32_16x16x32_bf16(
            asbf8(acur[dt]), bb, acc[dt][nt], 0, 0, 0);
    }
#pragma unroll
    for (int dt = 0; dt < 4; ++dt) acur[dt] = anxt[dt];
  }

  // ---- epilogue: fp32 out [b][d][n]
#pragma unroll
  for (int dt = 0; dt < 4; ++dt) {
    int dbase = d0 + dt * 16 + q * 4;
    float4 bi = *(const float4*)(b2 + dbase);
    float bv[4] = {bi.x, bi.y, bi.z, bi.w};
#pragma unroll
    for (int nt = 0; nt < 4; ++nt) {
      int gn = n0 + nt * 16 + lm;
      if (gn < NODES) {
        float* op = out + ((size_t)(b * CO + dbase) * NODES) + gn;
#pragma unroll
        for (int r = 0; r < 4; ++r)
          op[(size_t)r * NODES] = fmaxf(acc[dt][nt][r] + bv[r], 0.f);
      }
    }
  }
}

// ---------------------------------------------------------------------------
extern "C" void kernel_launch(void* const* d_in, const int* in_sizes, int n_in,
                              void* d_out, int out_size, void* d_ws, size_t ws_size,
                              hipStream_t stream) {
  const float* x  = (const float*)d_in[0];
  const int*   ei = (const int*)d_in[1];   // (2,B,N,K); first half = targets
  const float* W1 = (const float*)d_in[2];
  const float* b1 = (const float*)d_in[3];
  const float* Wp = (const float*)d_in[4];
  const float* bp = (const float*)d_in[5];
  const float* W2 = (const float*)d_in[6];
  const float* b2 = (const float*)d_in[7];
  float* out = (float*)d_out;

  unsigned short* ws  = (unsigned short*)d_ws;
  unsigned short* h_t = ws;                                   // [B][N][128] bf16
  unsigned short* z_t = h_t + (size_t)BATCH * NODES * CH;     // [B][N][128] bf16
  unsigned short* W1b = z_t + (size_t)BATCH * NODES * CH;
  unsigned short* Wpb = W1b + CH * CH;
  unsigned short* W2b = Wpb + CH * CH;

  prep<<<96, 256, 0, stream>>>(W1, Wp, W2, W1b, Wpb, W2b);

  const int NT = (NODES + 63) / 64;   // 157
  fused_hz<<<dim3(NT, BATCH), 256, 0, stream>>>(W1b, b1, Wpb, bp, x, h_t, z_t);
  out_kernel<<<BATCH * NT, 256, 0, stream>>>(h_t, z_t, ei, W2b, b2, out);
}